// Round 1
// baseline (370.974 us; speedup 1.0000x reference)
//
#include <hip/hip_runtime.h>
#include <hip/hip_bf16.h>
#include <math.h>

#define TAU 0.75f

// ---------------------------------------------------------------------------
// Prelude: everything except the conv. Single block, 256 threads.
// Outputs: W_upd -> d_out tail; cw (128*64*3), fsc (128), badd (128) -> d_ws.
// out[b][o][l] = fsc[o] * conv(x, cw)[b][o][l] + badd[o]
// ---------------------------------------------------------------------------
__global__ __launch_bounds__(256) void prelude_kernel(
    const float* __restrict__ grads, const float* __restrict__ W,
    const float* __restrict__ ctrl_w, const float* __restrict__ ctrl_b,
    const float* __restrict__ cw_w, const float* __restrict__ cw_b,
    const float* __restrict__ cb_w, const float* __restrict__ cb_b,
    const float* __restrict__ cf_w, const float* __restrict__ cf_b,
    const int* __restrict__ trigger,
    const float* __restrict__ conv_weight, const float* __restrict__ bias_param,
    float* __restrict__ W_out, float* __restrict__ cw_out,
    float* __restrict__ fsc_out, float* __restrict__ badd_out)
{
    __shared__ float repS[4096];   // rep[c][h], c,h in [0,64)
    __shared__ float qS[448];      // q = [w(192) | b(128) | f(128)]
    __shared__ float owS[448];     // old_w
    __shared__ float attS[32];
    __shared__ float sS[32];
    __shared__ float red[256];
    __shared__ int   idxS[2];
    __shared__ float vS[2];
    __shared__ float scaleS;

    const int t = threadIdx.x;
    const int trig = trigger[0];

    // Phase A: rep[c][h] = silu( g[c,:] . ctrl_w[h,:] + ctrl_b[h] ), g = grads.reshape(64,384)
    for (int e = t; e < 4096; e += 256) {
        const int c = e >> 6, h = e & 63;
        const float4* ga = (const float4*)(grads + c * 384);
        const float4* wa = (const float4*)(ctrl_w + h * 384);
        float dot = 0.f;
        #pragma unroll 4
        for (int d = 0; d < 96; d++) {
            float4 a = ga[d], b4 = wa[d];
            dot += a.x * b4.x + a.y * b4.y + a.z * b4.z + a.w * b4.w;
        }
        const float z = dot + ctrl_b[h];
        repS[e] = z / (1.f + expf(-z));   // silu
    }
    __syncthreads();

    // Phase B: q[e] — w at [c*3+j], b at [192+c*2+j], f at [320+c*2+j]
    for (int e = t; e < 448; e += 256) {
        const float* wv; float bias; int c;
        if (e < 192)      { c = e / 3;            const int j = e - c * 3; wv = cw_w + j * 64; bias = cw_b[j]; }
        else if (e < 320) { const int e2 = e - 192; c = e2 >> 1; const int j = e2 & 1; wv = cb_w + j * 64; bias = cb_b[j]; }
        else              { const int e2 = e - 320; c = e2 >> 1; const int j = e2 & 1; wv = cf_w + j * 64; bias = cf_b[j]; }
        const float* rr = repS + c * 64;
        float dot = 0.f;
        #pragma unroll 8
        for (int h = 0; h < 64; h++) dot += rr[h] * wv[h];
        qS[e] = dot + bias;
    }
    __syncthreads();

    // Phase C: s[m] = 2 * (q . W[:,m]); softmax; top-2 (serial in thread 0)
    if (t < 32) {
        float s = 0.f;
        for (int d = 0; d < 448; d++) s += qS[d] * W[d * 32 + t];
        sS[t] = 2.f * s;
    }
    __syncthreads();
    if (t == 0) {
        float mx = sS[0];
        for (int m = 1; m < 32; m++) mx = fmaxf(mx, sS[m]);
        float sum = 0.f;
        for (int m = 0; m < 32; m++) { const float e_ = expf(sS[m] - mx); attS[m] = e_; sum += e_; }
        const float inv = 1.f / sum;
        for (int m = 0; m < 32; m++) attS[m] *= inv;
        int i0 = 0; float v0 = attS[0];
        for (int m = 1; m < 32; m++) if (attS[m] > v0) { v0 = attS[m]; i0 = m; }  // ties: lowest idx
        int i1 = -1; float v1 = -1.f;
        for (int m = 0; m < 32; m++) { if (m == i0) continue; if (attS[m] > v1) { v1 = attS[m]; i1 = m; } }
        idxS[0] = i0; idxS[1] = i1; vS[0] = v0; vS[1] = v1;
    }
    __syncthreads();
    const int i0 = idxS[0], i1 = idxS[1];
    const float v0 = vS[0], v1 = vS[1];

    if (trig == 1) {
        // old_w[d] = W[d,i0]*i0 + W[d,i1]*i1   (yes, multiplied by the *indices*)
        for (int d = t; d < 448; d += 256)
            owS[d] = W[d * 32 + i0] * (float)i0 + W[d * 32 + i1] * (float)i1;
        __syncthreads();

        // pass 1: Frobenius norm^2 of W_new
        float ss = 0.f;
        for (int e = t; e < 14336; e += 256) {
            const int d = e >> 5, m = e & 31;
            const float wv = W[e];
            const float wn = (m == i0) ? (TAU * wv + (1.f - TAU) * owS[d] * v0)
                           : (m == i1) ? (TAU * wv + (1.f - TAU) * owS[d] * v1) : wv;
            ss += wn * wn;
        }
        red[t] = ss;
        __syncthreads();
        if (t == 0) {
            float tot = 0.f;
            for (int j = 0; j < 256; j++) tot += red[j];
            float n = sqrtf(tot);
            n = fmaxf(n, 1.f);            // relu(n-1)+1
            scaleS = 1.f / n;
        }
        __syncthreads();
        const float sc = scaleS;
        // pass 2: recompute and write normalized W_upd
        for (int e = t; e < 14336; e += 256) {
            const int d = e >> 5, m = e & 31;
            const float wv = W[e];
            const float wn = (m == i0) ? (TAU * wv + (1.f - TAU) * owS[d] * v0)
                           : (m == i1) ? (TAU * wv + (1.f - TAU) * owS[d] * v1) : wv;
            W_out[e] = wn * sc;
        }
    } else {
        for (int e = t; e < 14336; e += 256) W_out[e] = W[e];
        __syncthreads();
    }
    __syncthreads();

    // Phase E: per-channel scales and fused conv weights
    // b_flat[o] ~ q[192+o], f_flat[o] ~ q[320+o] (same row-major flattening)
    for (int o = t; o < 128; o += 256) {
        float bf = qS[192 + o], ff = qS[320 + o];
        if (trig == 1) {
            bf = TAU * bf + (1.f - TAU) * owS[192 + o];
            ff = TAU * ff + (1.f - TAU) * owS[320 + o];
        }
        fsc_out[o]  = ff;
        badd_out[o] = ff * bias_param[o] * bf;
    }
    for (int e = t; e < 24576; e += 256) {
        const int rem = e % 192;          // = i*3 + k
        float wf = qS[rem];
        if (trig == 1) wf = TAU * wf + (1.f - TAU) * owS[rem];
        cw_out[e] = conv_weight[e] * wf;
    }
}

// ---------------------------------------------------------------------------
// Conv: out[b][o][l] = fsc[o] * sum_{i,k} cw[o][i][k]*x[b][i][l+k-1] + badd[o]
// Each thread: 4 consecutive l, 8 output channels (acc[8][4]); x loaded once
// per i (float4 + 2 edge scalars), reused across the 8 o's. Weights are
// block-uniform -> scalar loads. Grid: 32 b * 16 o-groups * 4 l-chunks.
// ---------------------------------------------------------------------------
__global__ __launch_bounds__(256) void conv_kernel(
    const float* __restrict__ x, const float* __restrict__ cw,
    const float* __restrict__ fsc, const float* __restrict__ badd,
    float* __restrict__ out)
{
    const int bid   = blockIdx.x;
    const int b     = bid >> 6;       // / 64
    const int rem   = bid & 63;
    const int og    = rem >> 2;       // o-group of 8
    const int chunk = rem & 3;
    const int t     = threadIdx.x;
    const int l0    = chunk * 1024 + t * 4;

    float acc[8][4];
    #pragma unroll
    for (int oo = 0; oo < 8; oo++)
        #pragma unroll
        for (int v = 0; v < 4; v++) acc[oo][v] = 0.f;

    const float* xb = x + (size_t)b * 64 * 4096;
    const float* wbase = cw + og * 8 * 192;

    #pragma unroll 2
    for (int i = 0; i < 64; i++) {
        const float* xr = xb + (size_t)i * 4096;
        const float4 xm = *(const float4*)(xr + l0);
        const float xl = (l0 > 0)        ? xr[l0 - 1] : 0.f;
        const float xh = (l0 + 4 < 4096) ? xr[l0 + 4] : 0.f;
        const float xv[6] = {xl, xm.x, xm.y, xm.z, xm.w, xh};
        const float* wrow = wbase + i * 3;
        #pragma unroll
        for (int oo = 0; oo < 8; oo++) {
            const float w0 = wrow[oo * 192 + 0];
            const float w1 = wrow[oo * 192 + 1];
            const float w2 = wrow[oo * 192 + 2];
            #pragma unroll
            for (int v = 0; v < 4; v++)
                acc[oo][v] += w0 * xv[v] + w1 * xv[v + 1] + w2 * xv[v + 2];
        }
    }

    #pragma unroll
    for (int oo = 0; oo < 8; oo++) {
        const int o = og * 8 + oo;
        const float fs = fsc[o], ba = badd[o];
        float4 r;
        r.x = fs * acc[oo][0] + ba;
        r.y = fs * acc[oo][1] + ba;
        r.z = fs * acc[oo][2] + ba;
        r.w = fs * acc[oo][3] + ba;
        *(float4*)(out + ((size_t)(b * 128 + o)) * 4096 + l0) = r;
    }
}

extern "C" void kernel_launch(void* const* d_in, const int* in_sizes, int n_in,
                              void* d_out, int out_size, void* d_ws, size_t ws_size,
                              hipStream_t stream) {
    const float* x           = (const float*)d_in[0];
    const float* conv_weight = (const float*)d_in[1];
    const float* bias_param  = (const float*)d_in[2];
    const float* grads       = (const float*)d_in[3];
    const float* W           = (const float*)d_in[4];
    const float* ctrl_w      = (const float*)d_in[5];
    const float* ctrl_b      = (const float*)d_in[6];
    const float* cw_w        = (const float*)d_in[7];
    const float* cw_b        = (const float*)d_in[8];
    const float* cb_w        = (const float*)d_in[9];
    const float* cb_b        = (const float*)d_in[10];
    const float* cf_w        = (const float*)d_in[11];
    const float* cf_b        = (const float*)d_in[12];
    const int*   trigger     = (const int*)d_in[13];

    float* out   = (float*)d_out;
    float* W_out = out + (size_t)32 * 128 * 4096;   // 16777216
    float* cw    = (float*)d_ws;                    // 24576 floats
    float* fsc   = cw + 24576;                      // 128
    float* badd  = fsc + 128;                       // 128

    prelude_kernel<<<1, 256, 0, stream>>>(grads, W, ctrl_w, ctrl_b,
                                          cw_w, cw_b, cb_w, cb_b, cf_w, cf_b,
                                          trigger, conv_weight, bias_param,
                                          W_out, cw, fsc, badd);
    conv_kernel<<<2048, 256, 0, stream>>>(x, cw, fsc, badd, out);
}

// Round 2
// 121.844 us; speedup vs baseline: 3.0447x; 3.0447x over previous
//
#include <hip/hip_runtime.h>
#include <hip/hip_bf16.h>
#include <math.h>

#define TAU 0.75f

// ws layout (float offsets)
#define WS_Q     0      // q[448]
#define WS_NORM2 448    // base ||W||^2
#define WS_WQ    449    // blended w-scales [192]
#define WS_FSC   641    // f scale [128]
#define WS_BADD  769    // f*bias*b [128]
#define WS_OW    897    // old_w [448]
#define WS_SCALE 1345   // 1/norm
#define WS_V01   1346   // v0, v1
#define WS_I01   1348   // i0, i1 (as ints)
#define WS_CW    1352   // fused conv weights [24576]

// ---------------------------------------------------------------------------
// K1: blocks 0..63 -> chunk c: rep[c][0..63] then q entries for c.
//     block 64     -> base Frobenius norm^2 of W.
// ---------------------------------------------------------------------------
__global__ __launch_bounds__(256) void k1_rep_q(
    const float* __restrict__ grads, const float* __restrict__ ctrl_w,
    const float* __restrict__ ctrl_b,
    const float* __restrict__ cw_w, const float* __restrict__ cw_b,
    const float* __restrict__ cb_w, const float* __restrict__ cb_b,
    const float* __restrict__ cf_w, const float* __restrict__ cf_b,
    const float* __restrict__ W, float* __restrict__ ws)
{
    const int t = threadIdx.x;
    if (blockIdx.x == 64) {
        __shared__ float red[256];
        float ss = 0.f;
        for (int e = t; e < 3584; e += 256) {          // 14336 floats as float4
            const float4 w4 = ((const float4*)W)[e];
            ss += w4.x * w4.x + w4.y * w4.y + w4.z * w4.z + w4.w * w4.w;
        }
        red[t] = ss; __syncthreads();
        for (int s = 128; s > 0; s >>= 1) { if (t < s) red[t] += red[t + s]; __syncthreads(); }
        if (t == 0) ws[WS_NORM2] = red[0];
        return;
    }
    const int c = blockIdx.x;
    __shared__ float gS[384];
    __shared__ float repS[64];
    if (t < 96) ((float4*)gS)[t] = ((const float4*)(grads + c * 384))[t];
    __syncthreads();
    {   // rep[h] = silu(g_c . ctrl_w[h] + ctrl_b[h]); 4 lanes per h
        const int h = t >> 2, sub = t & 3;
        const float4* wa = (const float4*)(ctrl_w + h * 384) + sub * 24;
        const float4* ga = (const float4*)gS + sub * 24;
        float dot = 0.f;
        #pragma unroll
        for (int d = 0; d < 24; d++) {
            const float4 a = ga[d], b = wa[d];
            dot += a.x * b.x + a.y * b.y + a.z * b.z + a.w * b.w;
        }
        dot += __shfl_xor(dot, 1);
        dot += __shfl_xor(dot, 2);
        if (sub == 0) {
            const float z = dot + ctrl_b[h];
            repS[h] = z / (1.f + expf(-z));
        }
    }
    __syncthreads();
    if (t < 7) {   // 7 q entries for this chunk
        const float* wv; float bias; int e;
        if (t < 3)      { wv = cw_w + t * 64;       bias = cw_b[t];     e = 3 * c + t; }
        else if (t < 5) { const int j = t - 3; wv = cb_w + j * 64; bias = cb_b[j]; e = 192 + 2 * c + j; }
        else            { const int j = t - 5; wv = cf_w + j * 64; bias = cf_b[j]; e = 320 + 2 * c + j; }
        float dot = 0.f;
        #pragma unroll 8
        for (int h = 0; h < 64; h++) dot += repS[h] * wv[h];
        ws[WS_Q + e] = dot + bias;
    }
}

// ---------------------------------------------------------------------------
// K2: scores -> softmax -> top2 -> old_w -> norm correction -> scale; blends.
// One block, 256 threads, every phase wave-parallel except the 32-elem softmax.
// ---------------------------------------------------------------------------
__global__ __launch_bounds__(256) void k2_small(
    const float* __restrict__ W, const float* __restrict__ bias_param,
    const int* __restrict__ trigger, float* __restrict__ ws)
{
    __shared__ float qS[448], owS[448], sS[32], red[256];
    __shared__ int   idxS[2];
    __shared__ float vS[2];
    const int t = threadIdx.x;
    const int trig = trigger[0];

    for (int e = t; e < 448; e += 256) qS[e] = ws[WS_Q + e];
    __syncthreads();

    {   // s[m] = 2 * q . W[:,m]; 8 lanes per m
        const int m = t >> 3, sub = t & 7;
        float s = 0.f;
        for (int d = sub; d < 448; d += 8) s += qS[d] * W[d * 32 + m];
        s += __shfl_xor(s, 1); s += __shfl_xor(s, 2); s += __shfl_xor(s, 4);
        if (sub == 0) sS[m] = 2.f * s;
    }
    __syncthreads();
    if (t == 0) {
        float mx = sS[0];
        for (int m = 1; m < 32; m++) mx = fmaxf(mx, sS[m]);
        float sum = 0.f; float att[32];
        for (int m = 0; m < 32; m++) { att[m] = expf(sS[m] - mx); sum += att[m]; }
        const float inv = 1.f / sum;
        int i0 = 0; float v0 = att[0];
        for (int m = 1; m < 32; m++) if (att[m] > v0) { v0 = att[m]; i0 = m; }
        int i1 = -1; float v1 = -1.f;
        for (int m = 0; m < 32; m++) { if (m == i0) continue; if (att[m] > v1) { v1 = att[m]; i1 = m; } }
        idxS[0] = i0; idxS[1] = i1; vS[0] = v0 * inv; vS[1] = v1 * inv;
    }
    __syncthreads();
    const int i0 = idxS[0], i1 = idxS[1];
    const float v0 = vS[0], v1 = vS[1];

    // old_w
    for (int d = t; d < 448; d += 256)
        owS[d] = (trig == 1) ? (W[d * 32 + i0] * (float)i0 + W[d * 32 + i1] * (float)i1) : 0.f;
    __syncthreads();

    // norm correction over the two touched columns
    float corr = 0.f;
    if (trig == 1) {
        for (int d = t; d < 448; d += 256) {
            const float w0 = W[d * 32 + i0], w1 = W[d * 32 + i1];
            const float n0 = TAU * w0 + 0.25f * owS[d] * v0;
            const float n1 = TAU * w1 + 0.25f * owS[d] * v1;
            corr += n0 * n0 - w0 * w0 + n1 * n1 - w1 * w1;
        }
    }
    red[t] = corr; __syncthreads();
    for (int s = 128; s > 0; s >>= 1) { if (t < s) red[t] += red[t + s]; __syncthreads(); }
    if (t == 0) {
        float n = sqrtf(fmaxf(ws[WS_NORM2] + red[0], 0.f));
        n = fmaxf(n, 1.f);
        ws[WS_SCALE] = 1.f / n;
        ws[WS_V01] = v0; ws[WS_V01 + 1] = v1;
        ((int*)ws)[WS_I01] = i0; ((int*)ws)[WS_I01 + 1] = i1;
    }

    // blended scales (independent of scale)
    for (int e = t; e < 192; e += 256)
        ws[WS_WQ + e] = (trig == 1) ? (TAU * qS[e] + 0.25f * owS[e]) : qS[e];
    for (int o = t; o < 128; o += 256) {
        float bb = qS[192 + o], ff = qS[320 + o];
        if (trig == 1) {
            bb = TAU * bb + 0.25f * owS[192 + o];
            ff = TAU * ff + 0.25f * owS[320 + o];
        }
        ws[WS_FSC + o]  = ff;
        ws[WS_BADD + o] = ff * bias_param[o] * bb;
    }
    for (int d = t; d < 448; d += 256) ws[WS_OW + d] = owS[d];
}

// ---------------------------------------------------------------------------
// K3: finalize W_out (14336) + fused conv weights cw (24576). 152 blocks.
// ---------------------------------------------------------------------------
__global__ __launch_bounds__(256) void k3_finalize(
    const float* __restrict__ W, const float* __restrict__ conv_weight,
    const int* __restrict__ trigger, const float* __restrict__ ws,
    float* __restrict__ W_out, float* __restrict__ cw_out)
{
    const int e = blockIdx.x * 256 + threadIdx.x;
    const int trig = trigger[0];
    if (e < 14336) {
        const float wv = W[e];
        float wn = wv;
        if (trig == 1) {
            const int d = e >> 5, m = e & 31;
            const int i0 = ((const int*)ws)[WS_I01], i1 = ((const int*)ws)[WS_I01 + 1];
            if (m == i0)      wn = TAU * wv + 0.25f * ws[WS_OW + d] * ws[WS_V01];
            else if (m == i1) wn = TAU * wv + 0.25f * ws[WS_OW + d] * ws[WS_V01 + 1];
            wn *= ws[WS_SCALE];
        }
        W_out[e] = wn;
    } else {
        const int e2 = e - 14336;            // < 24576
        const int rem = e2 % 192;
        cw_out[e2] = conv_weight[e2] * ws[WS_WQ + rem];
    }
}

// ---------------------------------------------------------------------------
// Conv: out[b][o][l] = fsc[o]*conv + badd[o]. 8 o x 8 l per thread.
// Grid: 32 b * 16 og * 2 l-chunks = 1024 blocks.
// ---------------------------------------------------------------------------
__global__ __launch_bounds__(256) void conv_kernel(
    const float* __restrict__ x, const float* __restrict__ cw,
    const float* __restrict__ fsc, const float* __restrict__ badd,
    float* __restrict__ out)
{
    const int bid   = blockIdx.x;
    const int b     = bid >> 5;       // / 32
    const int rem   = bid & 31;
    const int og    = rem >> 1;       // o-group of 8
    const int chunk = rem & 1;
    const int t     = threadIdx.x;
    const int l0    = chunk * 2048 + t * 8;

    float acc[8][8];
    #pragma unroll
    for (int oo = 0; oo < 8; oo++)
        #pragma unroll
        for (int v = 0; v < 8; v++) acc[oo][v] = 0.f;

    const float* xb = x + (size_t)b * 64 * 4096;
    const float* wbase = cw + og * 8 * 192;

    for (int i = 0; i < 64; i++) {
        const float* xr = xb + (size_t)i * 4096;
        const float4 m0 = *(const float4*)(xr + l0);
        const float4 m1 = *(const float4*)(xr + l0 + 4);
        const float xl = (l0 > 0)        ? xr[l0 - 1] : 0.f;
        const float xh = (l0 + 8 < 4096) ? xr[l0 + 8] : 0.f;
        const float xv[10] = {xl, m0.x, m0.y, m0.z, m0.w, m1.x, m1.y, m1.z, m1.w, xh};
        const float* wrow = wbase + i * 3;
        #pragma unroll
        for (int oo = 0; oo < 8; oo++) {
            const float w0 = wrow[oo * 192 + 0];
            const float w1 = wrow[oo * 192 + 1];
            const float w2 = wrow[oo * 192 + 2];
            #pragma unroll
            for (int v = 0; v < 8; v++)
                acc[oo][v] += w0 * xv[v] + w1 * xv[v + 1] + w2 * xv[v + 2];
        }
    }

    #pragma unroll
    for (int oo = 0; oo < 8; oo++) {
        const int o = og * 8 + oo;
        const float fs = fsc[o], ba = badd[o];
        float* op = out + ((size_t)(b * 128 + o)) * 4096 + l0;
        float4 r0, r1;
        r0.x = fs * acc[oo][0] + ba; r0.y = fs * acc[oo][1] + ba;
        r0.z = fs * acc[oo][2] + ba; r0.w = fs * acc[oo][3] + ba;
        r1.x = fs * acc[oo][4] + ba; r1.y = fs * acc[oo][5] + ba;
        r1.z = fs * acc[oo][6] + ba; r1.w = fs * acc[oo][7] + ba;
        *(float4*)op = r0;
        *(float4*)(op + 4) = r1;
    }
}

extern "C" void kernel_launch(void* const* d_in, const int* in_sizes, int n_in,
                              void* d_out, int out_size, void* d_ws, size_t ws_size,
                              hipStream_t stream) {
    const float* x           = (const float*)d_in[0];
    const float* conv_weight = (const float*)d_in[1];
    const float* bias_param  = (const float*)d_in[2];
    const float* grads       = (const float*)d_in[3];
    const float* W           = (const float*)d_in[4];
    const float* ctrl_w      = (const float*)d_in[5];
    const float* ctrl_b      = (const float*)d_in[6];
    const float* cw_w        = (const float*)d_in[7];
    const float* cw_b        = (const float*)d_in[8];
    const float* cb_w        = (const float*)d_in[9];
    const float* cb_b        = (const float*)d_in[10];
    const float* cf_w        = (const float*)d_in[11];
    const float* cf_b        = (const float*)d_in[12];
    const int*   trigger     = (const int*)d_in[13];

    float* out   = (float*)d_out;
    float* W_out = out + (size_t)32 * 128 * 4096;   // 16777216
    float* ws    = (float*)d_ws;
    float* cw    = ws + WS_CW;
    float* fsc   = ws + WS_FSC;
    float* badd  = ws + WS_BADD;

    k1_rep_q<<<65, 256, 0, stream>>>(grads, ctrl_w, ctrl_b, cw_w, cw_b,
                                     cb_w, cb_b, cf_w, cf_b, W, ws);
    k2_small<<<1, 256, 0, stream>>>(W, bias_param, trigger, ws);
    k3_finalize<<<152, 256, 0, stream>>>(W, conv_weight, trigger, ws, W_out, cw);
    conv_kernel<<<1024, 256, 0, stream>>>(x, cw, fsc, badd, out);
}

// Round 3
// 60.299 us; speedup vs baseline: 6.1522x; 2.0207x over previous
//
#include <hip/hip_runtime.h>
#include <hip/hip_bf16.h>
#include <math.h>

#define TAU 0.75f

typedef _Float16 half8 __attribute__((ext_vector_type(8)));
typedef float    f32x4 __attribute__((ext_vector_type(4)));

// ws layout (float offsets)
#define WS_Q     0      // q[448]
#define WS_NORM2 448    // base ||W||^2
#define WS_WQ    449    // blended w-scales [192]
#define WS_FSC   641    // f scale [128]
#define WS_BADD  769    // f*bias*b [128]
#define WS_OW    897    // old_w [448]
#define WS_SCALE 1345   // 1/norm
#define WS_V01   1346   // v0, v1
#define WS_I01   1348   // i0, i1 (as ints)
#define WS_WF16  1352   // f16 fused conv weights [3][128][64] (12288 floats worth)

// ---------------------------------------------------------------------------
// K1: blocks 0..63 -> chunk c: rep then q entries. block 64 -> ||W||^2.
// ---------------------------------------------------------------------------
__global__ __launch_bounds__(256) void k1_rep_q(
    const float* __restrict__ grads, const float* __restrict__ ctrl_w,
    const float* __restrict__ ctrl_b,
    const float* __restrict__ cw_w, const float* __restrict__ cw_b,
    const float* __restrict__ cb_w, const float* __restrict__ cb_b,
    const float* __restrict__ cf_w, const float* __restrict__ cf_b,
    const float* __restrict__ W, float* __restrict__ ws)
{
    const int t = threadIdx.x;
    if (blockIdx.x == 64) {
        __shared__ float red[256];
        float ss = 0.f;
        for (int e = t; e < 3584; e += 256) {
            const float4 w4 = ((const float4*)W)[e];
            ss += w4.x * w4.x + w4.y * w4.y + w4.z * w4.z + w4.w * w4.w;
        }
        red[t] = ss; __syncthreads();
        for (int s = 128; s > 0; s >>= 1) { if (t < s) red[t] += red[t + s]; __syncthreads(); }
        if (t == 0) ws[WS_NORM2] = red[0];
        return;
    }
    const int c = blockIdx.x;
    __shared__ float gS[384];
    __shared__ float repS[64];
    if (t < 96) ((float4*)gS)[t] = ((const float4*)(grads + c * 384))[t];
    __syncthreads();
    {
        const int h = t >> 2, sub = t & 3;
        const float4* wa = (const float4*)(ctrl_w + h * 384) + sub * 24;
        const float4* ga = (const float4*)gS + sub * 24;
        float dot = 0.f;
        #pragma unroll
        for (int d = 0; d < 24; d++) {
            const float4 a = ga[d], b = wa[d];
            dot += a.x * b.x + a.y * b.y + a.z * b.z + a.w * b.w;
        }
        dot += __shfl_xor(dot, 1);
        dot += __shfl_xor(dot, 2);
        if (sub == 0) {
            const float z = dot + ctrl_b[h];
            repS[h] = z / (1.f + expf(-z));
        }
    }
    __syncthreads();
    if (t < 7) {
        const float* wv; float bias; int e;
        if (t < 3)      { wv = cw_w + t * 64;       bias = cw_b[t];     e = 3 * c + t; }
        else if (t < 5) { const int j = t - 3; wv = cb_w + j * 64; bias = cb_b[j]; e = 192 + 2 * c + j; }
        else            { const int j = t - 5; wv = cf_w + j * 64; bias = cf_b[j]; e = 320 + 2 * c + j; }
        float dot = 0.f;
        #pragma unroll 8
        for (int h = 0; h < 64; h++) dot += repS[h] * wv[h];
        ws[WS_Q + e] = dot + bias;
    }
}

// ---------------------------------------------------------------------------
// K2: scores -> softmax -> top2 -> old_w -> norm correction -> blends.
// ---------------------------------------------------------------------------
__global__ __launch_bounds__(256) void k2_small(
    const float* __restrict__ W, const float* __restrict__ bias_param,
    const int* __restrict__ trigger, float* __restrict__ ws)
{
    __shared__ float qS[448], owS[448], sS[32], red[256];
    __shared__ int   idxS[2];
    __shared__ float vS[2];
    const int t = threadIdx.x;
    const int trig = trigger[0];

    for (int e = t; e < 448; e += 256) qS[e] = ws[WS_Q + e];
    __syncthreads();

    {
        const int m = t >> 3, sub = t & 7;
        float s = 0.f;
        for (int d = sub; d < 448; d += 8) s += qS[d] * W[d * 32 + m];
        s += __shfl_xor(s, 1); s += __shfl_xor(s, 2); s += __shfl_xor(s, 4);
        if (sub == 0) sS[m] = 2.f * s;
    }
    __syncthreads();
    if (t == 0) {
        float mx = sS[0];
        for (int m = 1; m < 32; m++) mx = fmaxf(mx, sS[m]);
        float sum = 0.f; float att[32];
        for (int m = 0; m < 32; m++) { att[m] = expf(sS[m] - mx); sum += att[m]; }
        const float inv = 1.f / sum;
        int i0 = 0; float v0 = att[0];
        for (int m = 1; m < 32; m++) if (att[m] > v0) { v0 = att[m]; i0 = m; }
        int i1 = -1; float v1 = -1.f;
        for (int m = 0; m < 32; m++) { if (m == i0) continue; if (att[m] > v1) { v1 = att[m]; i1 = m; } }
        idxS[0] = i0; idxS[1] = i1; vS[0] = v0 * inv; vS[1] = v1 * inv;
    }
    __syncthreads();
    const int i0 = idxS[0], i1 = idxS[1];
    const float v0 = vS[0], v1 = vS[1];

    for (int d = t; d < 448; d += 256)
        owS[d] = (trig == 1) ? (W[d * 32 + i0] * (float)i0 + W[d * 32 + i1] * (float)i1) : 0.f;
    __syncthreads();

    float corr = 0.f;
    if (trig == 1) {
        for (int d = t; d < 448; d += 256) {
            const float w0 = W[d * 32 + i0], w1 = W[d * 32 + i1];
            const float n0 = TAU * w0 + 0.25f * owS[d] * v0;
            const float n1 = TAU * w1 + 0.25f * owS[d] * v1;
            corr += n0 * n0 - w0 * w0 + n1 * n1 - w1 * w1;
        }
    }
    red[t] = corr; __syncthreads();
    for (int s = 128; s > 0; s >>= 1) { if (t < s) red[t] += red[t + s]; __syncthreads(); }
    if (t == 0) {
        float n = sqrtf(fmaxf(ws[WS_NORM2] + red[0], 0.f));
        n = fmaxf(n, 1.f);
        ws[WS_SCALE] = 1.f / n;
        ws[WS_V01] = v0; ws[WS_V01 + 1] = v1;
        ((int*)ws)[WS_I01] = i0; ((int*)ws)[WS_I01 + 1] = i1;
    }

    for (int e = t; e < 192; e += 256)
        ws[WS_WQ + e] = (trig == 1) ? (TAU * qS[e] + 0.25f * owS[e]) : qS[e];
    for (int o = t; o < 128; o += 256) {
        float bb = qS[192 + o], ff = qS[320 + o];
        if (trig == 1) {
            bb = TAU * bb + 0.25f * owS[192 + o];
            ff = TAU * ff + 0.25f * owS[320 + o];
        }
        ws[WS_FSC + o]  = ff;
        ws[WS_BADD + o] = ff * bias_param[o] * bb;
    }
    for (int d = t; d < 448; d += 256) ws[WS_OW + d] = owS[d];
}

// ---------------------------------------------------------------------------
// K3: W_out (14336) + fused f16 weight planes wf[k][o][i] (24576). 152 blocks.
// ---------------------------------------------------------------------------
__global__ __launch_bounds__(256) void k3_finalize(
    const float* __restrict__ W, const float* __restrict__ conv_weight,
    const int* __restrict__ trigger, float* __restrict__ ws,
    float* __restrict__ W_out, _Float16* __restrict__ wf_out)
{
    const int e = blockIdx.x * 256 + threadIdx.x;
    const int trig = trigger[0];
    if (e < 14336) {
        const float wv = W[e];
        float wn = wv;
        if (trig == 1) {
            const int d = e >> 5, m = e & 31;
            const int i0 = ((const int*)ws)[WS_I01], i1 = ((const int*)ws)[WS_I01 + 1];
            if (m == i0)      wn = TAU * wv + 0.25f * ws[WS_OW + d] * ws[WS_V01];
            else if (m == i1) wn = TAU * wv + 0.25f * ws[WS_OW + d] * ws[WS_V01 + 1];
            wn *= ws[WS_SCALE];
        }
        W_out[e] = wn;
    } else {
        const int e2 = e - 14336;            // < 24576 : (o*64+i)*3+kk
        const int o   = e2 / 192;
        const int rem = e2 - o * 192;        // i*3+kk
        const int i   = rem / 3;
        const int kk  = rem - i * 3;
        const float v = conv_weight[e2] * ws[WS_WQ + rem];
        wf_out[(kk * 128 + o) * 64 + i] = (_Float16)v;
    }
}

// ---------------------------------------------------------------------------
// Conv via f16 MFMA. Block: 128 o x 128 l for one batch. 4 waves x (32o,128l).
// LDS: x tile transposed [l(130)][i(64)] f16, stride 72 (16B-aligned rows,
// conflict-free b128 reads). out = fsc[o]*conv + badd[o].
// Grid: 32 b * 32 l-tiles = 1024 blocks.
// ---------------------------------------------------------------------------
__global__ __launch_bounds__(256) void conv_mfma(
    const float* __restrict__ x, const _Float16* __restrict__ wf,
    const float* __restrict__ fsc, const float* __restrict__ badd,
    float* __restrict__ out)
{
    __shared__ __align__(16) _Float16 xs[130 * 72];

    const int t    = threadIdx.x;
    const int wv   = t >> 6;
    const int lane = t & 63;
    const int lrow = lane & 15;
    const int lgrp = lane >> 4;
    const int b    = blockIdx.x >> 5;
    const int l0   = (blockIdx.x & 31) * 128;
    const int obase = wv * 32;

    // stage x[b][i][l0-1 .. l0+128] -> xs[c][i]  (c = l - (l0-1))
    const float* xb = x + (size_t)b * 64 * 4096;
    for (int idx = t; idx < 130 * 64; idx += 256) {
        const int i = idx & 63, c = idx >> 6;
        const int l = l0 - 1 + c;
        const float v = (l >= 0 && l < 4096) ? xb[(size_t)i * 4096 + l] : 0.f;
        xs[c * 72 + i] = (_Float16)v;
    }

    // A fragments: wf[kk][o][i], o = obase + of*16 + lrow, i = ch*32 + lgrp*8 + j
    half8 A[2][2][3];
    #pragma unroll
    for (int of = 0; of < 2; of++)
        #pragma unroll
        for (int ch = 0; ch < 2; ch++)
            #pragma unroll
            for (int kk = 0; kk < 3; kk++)
                A[of][ch][kk] = *(const half8*)(wf + ((kk * 128 + obase + of * 16 + lrow) * 64 + ch * 32 + lgrp * 8));

    f32x4 acc[2][8];
    #pragma unroll
    for (int of = 0; of < 2; of++)
        #pragma unroll
        for (int lf = 0; lf < 8; lf++) acc[of][lf] = (f32x4)0.f;

    __syncthreads();

    #pragma unroll
    for (int ch = 0; ch < 2; ch++) {
        #pragma unroll
        for (int kk = 0; kk < 3; kk++) {
            half8 B[8];
            #pragma unroll
            for (int lf = 0; lf < 8; lf++)
                B[lf] = *(const half8*)(xs + (lf * 16 + lrow + kk) * 72 + ch * 32 + lgrp * 8);
            #pragma unroll
            for (int of = 0; of < 2; of++)
                #pragma unroll
                for (int lf = 0; lf < 8; lf++)
                    acc[of][lf] = __builtin_amdgcn_mfma_f32_16x16x32_f16(A[of][ch][kk], B[lf], acc[of][lf], 0, 0, 0);
        }
    }

    // epilogue: o = obase + of*16 + lgrp*4 + r ; l = l0 + lf*16 + lrow
    #pragma unroll
    for (int of = 0; of < 2; of++) {
        const int ob = obase + of * 16 + lgrp * 4;
        float fs[4], ba[4];
        #pragma unroll
        for (int r = 0; r < 4; r++) { fs[r] = fsc[ob + r]; ba[r] = badd[ob + r]; }
        #pragma unroll
        for (int lf = 0; lf < 8; lf++) {
            const int l = l0 + lf * 16 + lrow;
            float* op = out + ((size_t)(b * 128 + ob)) * 4096 + l;
            #pragma unroll
            for (int r = 0; r < 4; r++)
                op[(size_t)r * 4096] = fs[r] * acc[of][lf][r] + ba[r];
        }
    }
}

extern "C" void kernel_launch(void* const* d_in, const int* in_sizes, int n_in,
                              void* d_out, int out_size, void* d_ws, size_t ws_size,
                              hipStream_t stream) {
    const float* x           = (const float*)d_in[0];
    const float* conv_weight = (const float*)d_in[1];
    const float* bias_param  = (const float*)d_in[2];
    const float* grads       = (const float*)d_in[3];
    const float* W           = (const float*)d_in[4];
    const float* ctrl_w      = (const float*)d_in[5];
    const float* ctrl_b      = (const float*)d_in[6];
    const float* cw_w        = (const float*)d_in[7];
    const float* cw_b        = (const float*)d_in[8];
    const float* cb_w        = (const float*)d_in[9];
    const float* cb_b        = (const float*)d_in[10];
    const float* cf_w        = (const float*)d_in[11];
    const float* cf_b        = (const float*)d_in[12];
    const int*   trigger     = (const int*)d_in[13];

    float* out   = (float*)d_out;
    float* W_out = out + (size_t)32 * 128 * 4096;   // 16777216
    float* ws    = (float*)d_ws;
    _Float16* wf = (_Float16*)(ws + WS_WF16);
    float* fsc   = ws + WS_FSC;
    float* badd  = ws + WS_BADD;

    k1_rep_q<<<65, 256, 0, stream>>>(grads, ctrl_w, ctrl_b, cw_w, cw_b,
                                     cb_w, cb_b, cf_w, cf_b, W, ws);
    k2_small<<<1, 256, 0, stream>>>(W, bias_param, trigger, ws);
    k3_finalize<<<152, 256, 0, stream>>>(W, conv_weight, trigger, ws, W_out, wf);
    conv_mfma<<<1024, 256, 0, stream>>>(x, wf, fsc, badd, out);
}

// Round 4
// 58.502 us; speedup vs baseline: 6.3412x; 1.0307x over previous
//
#include <hip/hip_runtime.h>
#include <hip/hip_bf16.h>
#include <math.h>

#define TAU 0.75f

typedef _Float16 half8 __attribute__((ext_vector_type(8)));
typedef float    f32x4 __attribute__((ext_vector_type(4)));

// ws layout (float offsets)
#define WS_REP   0      // rep[64][64]
#define WS_NORM2 4096   // base ||W||^2
#define WS_FSC   4100   // f scale [128]
#define WS_BADD  4228   // f*bias*b [128]
#define WS_WF16  4360   // f16 fused conv weights [3][128][64] (12288 floats; 16B-aligned)

// ---------------------------------------------------------------------------
// K1: blocks 0..255 -> (chunk c = b>>2, h-quarter hq = b&3): rep[c][hq*16..+15].
//     block 256     -> base Frobenius norm^2 of W.
// ---------------------------------------------------------------------------
__global__ __launch_bounds__(256) void k1_rep(
    const float* __restrict__ grads, const float* __restrict__ ctrl_w,
    const float* __restrict__ ctrl_b, const float* __restrict__ W,
    float* __restrict__ ws)
{
    const int t = threadIdx.x;
    if (blockIdx.x == 256) {
        __shared__ float red[256];
        float ss = 0.f;
        for (int e = t; e < 3584; e += 256) {
            const float4 w4 = ((const float4*)W)[e];
            ss += w4.x * w4.x + w4.y * w4.y + w4.z * w4.z + w4.w * w4.w;
        }
        red[t] = ss; __syncthreads();
        for (int s = 128; s > 0; s >>= 1) { if (t < s) red[t] += red[t + s]; __syncthreads(); }
        if (t == 0) ws[WS_NORM2] = red[0];
        return;
    }
    const int c = blockIdx.x >> 2, hq = blockIdx.x & 3;
    __shared__ float gS[384];
    if (t < 96) ((float4*)gS)[t] = ((const float4*)(grads + c * 384))[t];
    __syncthreads();
    const int hl = t >> 4, sub = t & 15;
    const int h = hq * 16 + hl;
    const float4* wa = (const float4*)(ctrl_w + h * 384) + sub * 6;
    const float4* ga = (const float4*)gS + sub * 6;
    float dot = 0.f;
    #pragma unroll
    for (int d = 0; d < 6; d++) {
        const float4 a = ga[d], b = wa[d];
        dot += a.x * b.x + a.y * b.y + a.z * b.z + a.w * b.w;
    }
    dot += __shfl_xor(dot, 1); dot += __shfl_xor(dot, 2);
    dot += __shfl_xor(dot, 4); dot += __shfl_xor(dot, 8);
    if (sub == 0) {
        const float z = dot + ctrl_b[h];
        ws[WS_REP + c * 64 + h] = z / (1.f + expf(-z));
    }
}

// ---------------------------------------------------------------------------
// K23: each of 152 blocks redundantly computes q -> scores -> softmax -> top2
// -> old_w -> norm correction (all identical, deterministic), then writes its
// 256-element slice of {W_out[14336], wf[24576]}. Block 0 also writes fsc/badd.
// ---------------------------------------------------------------------------
__global__ __launch_bounds__(256) void k23(
    const float* __restrict__ W, const float* __restrict__ bias_param,
    const float* __restrict__ conv_weight,
    const float* __restrict__ cw_w, const float* __restrict__ cw_b,
    const float* __restrict__ cb_w, const float* __restrict__ cb_b,
    const float* __restrict__ cf_w, const float* __restrict__ cf_b,
    const int* __restrict__ trigger, float* __restrict__ ws,
    float* __restrict__ W_out, _Float16* __restrict__ wf_out)
{
    __shared__ float repS[4096];
    __shared__ float qS[448], owS[448], wqS[192], sS[32], red[256];
    __shared__ int   idxS[2];
    __shared__ float vS[2], scaleS;

    const int t = threadIdx.x;
    const int trig = trigger[0];

    for (int e = t; e < 1024; e += 256)
        ((float4*)repS)[e] = ((const float4*)(ws + WS_REP))[e];
    __syncthreads();

    // q[448]
    for (int e = t; e < 448; e += 256) {
        const float* wv; float bias; int c;
        if (e < 192)      { c = e / 3;              const int j = e - c * 3; wv = cw_w + j * 64; bias = cw_b[j]; }
        else if (e < 320) { const int e2 = e - 192; c = e2 >> 1; const int j = e2 & 1; wv = cb_w + j * 64; bias = cb_b[j]; }
        else              { const int e2 = e - 320; c = e2 >> 1; const int j = e2 & 1; wv = cf_w + j * 64; bias = cf_b[j]; }
        const float* rr = repS + c * 64;
        float dot = 0.f;
        #pragma unroll 8
        for (int h = 0; h < 64; h++) dot += rr[h] * wv[h];
        qS[e] = dot + bias;
    }
    __syncthreads();

    // scores s[m] = 2 * q . W[:,m]
    {
        const int m = t >> 3, sub = t & 7;
        float s = 0.f;
        for (int d = sub; d < 448; d += 8) s += qS[d] * W[d * 32 + m];
        s += __shfl_xor(s, 1); s += __shfl_xor(s, 2); s += __shfl_xor(s, 4);
        if (sub == 0) sS[m] = 2.f * s;
    }
    __syncthreads();
    if (t == 0) {
        float mx = sS[0];
        for (int m = 1; m < 32; m++) mx = fmaxf(mx, sS[m]);
        float sum = 0.f; float att[32];
        for (int m = 0; m < 32; m++) { att[m] = expf(sS[m] - mx); sum += att[m]; }
        const float inv = 1.f / sum;
        int i0 = 0; float v0 = att[0];
        for (int m = 1; m < 32; m++) if (att[m] > v0) { v0 = att[m]; i0 = m; }
        int i1 = -1; float v1 = -1.f;
        for (int m = 0; m < 32; m++) { if (m == i0) continue; if (att[m] > v1) { v1 = att[m]; i1 = m; } }
        idxS[0] = i0; idxS[1] = i1; vS[0] = v0 * inv; vS[1] = v1 * inv;
    }
    __syncthreads();
    const int i0 = idxS[0], i1 = idxS[1];
    const float v0 = vS[0], v1 = vS[1];

    for (int d = t; d < 448; d += 256)
        owS[d] = (trig == 1) ? (W[d * 32 + i0] * (float)i0 + W[d * 32 + i1] * (float)i1) : 0.f;
    __syncthreads();

    float corr = 0.f;
    if (trig == 1) {
        for (int d = t; d < 448; d += 256) {
            const float w0 = W[d * 32 + i0], w1 = W[d * 32 + i1];
            const float n0 = TAU * w0 + 0.25f * owS[d] * v0;
            const float n1 = TAU * w1 + 0.25f * owS[d] * v1;
            corr += n0 * n0 - w0 * w0 + n1 * n1 - w1 * w1;
        }
    }
    red[t] = corr; __syncthreads();
    for (int s = 128; s > 0; s >>= 1) { if (t < s) red[t] += red[t + s]; __syncthreads(); }
    if (t == 0) {
        float n = sqrtf(fmaxf(ws[WS_NORM2] + red[0], 0.f));
        scaleS = 1.f / fmaxf(n, 1.f);
    }
    if (t < 192) wqS[t] = (trig == 1) ? (TAU * qS[t] + 0.25f * owS[t]) : qS[t];
    __syncthreads();

    if (blockIdx.x == 0 && t < 128) {
        float bb = qS[192 + t], ff = qS[320 + t];
        if (trig == 1) {
            bb = TAU * bb + 0.25f * owS[192 + t];
            ff = TAU * ff + 0.25f * owS[320 + t];
        }
        ws[WS_FSC + t]  = ff;
        ws[WS_BADD + t] = ff * bias_param[t] * bb;
    }

    // output slice
    const int g = blockIdx.x * 256 + t;
    if (g < 14336) {
        const float wv = W[g];
        float wn = wv;
        if (trig == 1) {
            const int d = g >> 5, m = g & 31;
            if (m == i0)      wn = TAU * wv + 0.25f * owS[d] * v0;
            else if (m == i1) wn = TAU * wv + 0.25f * owS[d] * v1;
            wn *= scaleS;
        }
        W_out[g] = wn;
    } else {
        const int e2 = g - 14336;            // (o*64+i)*3+kk
        const int o   = e2 / 192;
        const int rem = e2 - o * 192;
        const int i   = rem / 3;
        const int kk  = rem - i * 3;
        wf_out[(kk * 128 + o) * 64 + i] = (_Float16)(conv_weight[e2] * wqS[rem]);
    }
}

// ---------------------------------------------------------------------------
// Conv via f16 MFMA. Block: 128 o x 128 l, 4 waves x (32o,128l).
// Staging now coalesced: lanes (c-chunk fast, i slow) -> 16 rows x 64B per
// wave instr; transposed LDS writes are 4x ds_write_b16 (~4-way conflict, ok).
// Grid: 32 b * 32 l-tiles = 1024 blocks (exactly 4/CU).
// ---------------------------------------------------------------------------
__global__ __launch_bounds__(256) void conv_mfma(
    const float* __restrict__ x, const _Float16* __restrict__ wf,
    const float* __restrict__ fsc, const float* __restrict__ badd,
    float* __restrict__ out)
{
    __shared__ __align__(16) _Float16 xs[130 * 72];

    const int t    = threadIdx.x;
    const int wv   = t >> 6;
    const int lane = t & 63;
    const int lrow = lane & 15;
    const int lgrp = lane >> 4;
    const int b    = blockIdx.x >> 5;
    const int l0   = (blockIdx.x & 31) * 128;
    const int obase = wv * 32;

    const float* xb = x + (size_t)b * 64 * 4096;
    const int ci = t & 3;          // c-chunk within 16-c group
    const int ir = t >> 2;         // row i, 0..63

    // edge values (c=0 -> l0-1, c=129 -> l0+128)
    float xe = 0.f;
    const int ei = t & 63, side = t >> 6;
    if (t < 128) {
        const int l = side ? (l0 + 128) : (l0 - 1);
        xe = (l >= 0 && l < 4096) ? xb[(size_t)ei * 4096 + l] : 0.f;
    }

    // A fragments: wf[kk][o][i]
    half8 A[2][2][3];
    #pragma unroll
    for (int of = 0; of < 2; of++)
        #pragma unroll
        for (int ch = 0; ch < 2; ch++)
            #pragma unroll
            for (int kk = 0; kk < 3; kk++)
                A[of][ch][kk] = *(const half8*)(wf + ((kk * 128 + obase + of * 16 + lrow) * 64 + ch * 32 + lgrp * 8));

    // staged x: 2 batches of 4 float4 loads, then transposed f16 writes
    #pragma unroll
    for (int half = 0; half < 2; half++) {
        float4 xr[4];
        #pragma unroll
        for (int it = 0; it < 4; it++)
            xr[it] = *(const float4*)(xb + (size_t)ir * 4096 + l0 + (half * 4 + it) * 16 + ci * 4);
        #pragma unroll
        for (int it = 0; it < 4; it++) {
            _Float16* p = xs + ((half * 4 + it) * 16 + ci * 4 + 1) * 72 + ir;
            p[0]   = (_Float16)xr[it].x;
            p[72]  = (_Float16)xr[it].y;
            p[144] = (_Float16)xr[it].z;
            p[216] = (_Float16)xr[it].w;
        }
    }
    if (t < 128) xs[(side ? 129 : 0) * 72 + ei] = (_Float16)xe;

    f32x4 acc[2][8];
    #pragma unroll
    for (int of = 0; of < 2; of++)
        #pragma unroll
        for (int lf = 0; lf < 8; lf++) acc[of][lf] = (f32x4)0.f;

    __syncthreads();

    #pragma unroll
    for (int ch = 0; ch < 2; ch++) {
        #pragma unroll
        for (int kk = 0; kk < 3; kk++) {
            half8 B[8];
            #pragma unroll
            for (int lf = 0; lf < 8; lf++)
                B[lf] = *(const half8*)(xs + (lf * 16 + lrow + kk) * 72 + ch * 32 + lgrp * 8);
            #pragma unroll
            for (int of = 0; of < 2; of++)
                #pragma unroll
                for (int lf = 0; lf < 8; lf++)
                    acc[of][lf] = __builtin_amdgcn_mfma_f32_16x16x32_f16(A[of][ch][kk], B[lf], acc[of][lf], 0, 0, 0);
        }
    }

    // epilogue: o = obase + of*16 + lgrp*4 + r ; l = l0 + lf*16 + lrow
    #pragma unroll
    for (int of = 0; of < 2; of++) {
        const int ob = obase + of * 16 + lgrp * 4;
        float fs[4], ba[4];
        #pragma unroll
        for (int r = 0; r < 4; r++) { fs[r] = fsc[ob + r]; ba[r] = badd[ob + r]; }
        #pragma unroll
        for (int lf = 0; lf < 8; lf++) {
            const int l = l0 + lf * 16 + lrow;
            float* op = out + ((size_t)(b * 128 + ob)) * 4096 + l;
            #pragma unroll
            for (int r = 0; r < 4; r++)
                op[(size_t)r * 4096] = fs[r] * acc[of][lf][r] + ba[r];
        }
    }
}

extern "C" void kernel_launch(void* const* d_in, const int* in_sizes, int n_in,
                              void* d_out, int out_size, void* d_ws, size_t ws_size,
                              hipStream_t stream) {
    const float* x           = (const float*)d_in[0];
    const float* conv_weight = (const float*)d_in[1];
    const float* bias_param  = (const float*)d_in[2];
    const float* grads       = (const float*)d_in[3];
    const float* W           = (const float*)d_in[4];
    const float* ctrl_w      = (const float*)d_in[5];
    const float* ctrl_b      = (const float*)d_in[6];
    const float* cw_w        = (const float*)d_in[7];
    const float* cw_b        = (const float*)d_in[8];
    const float* cb_w        = (const float*)d_in[9];
    const float* cb_b        = (const float*)d_in[10];
    const float* cf_w        = (const float*)d_in[11];
    const float* cf_b        = (const float*)d_in[12];
    const int*   trigger     = (const int*)d_in[13];

    float* out   = (float*)d_out;
    float* W_out = out + (size_t)32 * 128 * 4096;   // 16777216
    float* ws    = (float*)d_ws;
    _Float16* wfp = (_Float16*)(ws + WS_WF16);
    float* fsc   = ws + WS_FSC;
    float* badd  = ws + WS_BADD;

    k1_rep<<<257, 256, 0, stream>>>(grads, ctrl_w, ctrl_b, W, ws);
    k23<<<152, 256, 0, stream>>>(W, bias_param, conv_weight,
                                 cw_w, cw_b, cb_w, cb_b, cf_w, cf_b,
                                 trigger, ws, W_out, wfp);
    conv_mfma<<<1024, 256, 0, stream>>>(x, wfp, fsc, badd, out);
}